// Round 10
// baseline (637.824 us; speedup 1.0000x reference)
//
#include <hip/hip_runtime.h>
#include <float.h>

#define NN 256
#define KK 20

// Coarse phase fence: forbid the scheduler from hoisting later phases'
// (global weight) loads across phase boundaries. Cross-phase hoisting is the
// spill source: no single phase needs >256 VGPRs, yet r7 hit the 256 cap and
// still spilled ~97MB/launch. Used ONLY at phase boundaries (9 sites), not
// inside hot loops (m141 lesson).
#define SB() __builtin_amdgcn_sched_barrier(0)

__device__ __forceinline__ float med3f(float a, float b, float c) {
    return __builtin_amdgcn_fmed3f(a, b, c);
}

// Distance helpers: called from BOTH pass1 (value top-k) and pass2 (index
// recovery) — identical inlined expression trees guarantee bit-identical d.
__device__ __forceinline__ float dist2d(const float* __restrict__ s_xyq,
                                        float xi0, float xi1, float sqi,
                                        int j, int t) {
    float4 q = ((const float4*)s_xyq)[j];          // uniform -> LDS broadcast
    float dot = xi0*q.x + xi1*q.y;
    float d = (sqi + q.z) - 2.0f*dot;
    return (j == t) ? __builtin_inff() : d;        // self-exclusion, branchless
}

__device__ __forceinline__ float dist16f(const float* __restrict__ s_x1,
                                         const float* __restrict__ s_sq,
                                         const float* __restrict__ x1f,
                                         float sq2, int j, int t) {
    const float4* xp = (const float4*)(s_x1 + (j << 4));   // uniform broadcast
    float4 q0 = xp[0], q1 = xp[1], q2 = xp[2], q3 = xp[3];
    float dot;
    dot  = x1f[0]*q0.x;  dot += x1f[1]*q0.y;  dot += x1f[2]*q0.z;  dot += x1f[3]*q0.w;
    dot += x1f[4]*q1.x;  dot += x1f[5]*q1.y;  dot += x1f[6]*q1.z;  dot += x1f[7]*q1.w;
    dot += x1f[8]*q2.x;  dot += x1f[9]*q2.y;  dot += x1f[10]*q2.z; dot += x1f[11]*q2.w;
    dot += x1f[12]*q3.x; dot += x1f[13]*q3.y; dot += x1f[14]*q3.z; dot += x1f[15]*q3.w;
    float d = (sq2 + s_sq[j]) - 2.0f*dot;
    return (j == t) ? __builtin_inff() : d;
}

// launch_bounds(256,1): grid 512 on 256 CUs = 2 blocks/CU max residency; keep
// the VGPR cap at the architectural 256 so intra-phase demand (~150) fits.
__global__ __launch_bounds__(256, 1)
void Net_35055523070563_kernel(
    const float* __restrict__ x,
    const float* __restrict__ c1_w0, const float* __restrict__ c1_b0,
    const float* __restrict__ c1_w1, const float* __restrict__ c1_b1,
    const float* __restrict__ c1_w2, const float* __restrict__ c1_b2,
    const float* __restrict__ c2_w0, const float* __restrict__ c2_b0,
    const float* __restrict__ lin1_w, const float* __restrict__ lin1_b,
    const float* __restrict__ m_w0, const float* __restrict__ m_b0,
    const float* __restrict__ m_w1, const float* __restrict__ m_b1,
    const float* __restrict__ m_w2, const float* __restrict__ m_b2,
    float* __restrict__ out)
{
    // Phase-multiplexed region R (36 KB):
    //   P1 : s_xyq[256*4] @ 0..1023 ; Leq bytes @ floats 1024..1599
    //   P2 : s_v[256*20]  @ 0..5119 ; s_x1[256*16] @ 5120..9215
    //   P3 : s_sq[256] @ 0..255 ; Leq @ 1024..1599 ; s_x1 @ 5120..9215
    //   P4 : c2t[32*256]  @ 0..8191   (transposed for conflict-free gather)
    //   P5 : shW[48*32]   @ 0..1535
    __shared__ __align__(16) float R[9216];
    __shared__ unsigned char s_ki[(KK + 1) * NN];   // 20 rows + trash row, lane-minor
    __shared__ float s_w0d[32], s_w0b[32], s_b0[16], s_b1[16], s_b2[16];
    __shared__ __align__(16) float s_W1[256], s_W2[256];
    __shared__ __align__(16) float s_wtd[512], s_wb[512], s_bc[32];
    __shared__ float s_part[128], s_pooled[128], s_head[64];

    float* s_xyq = R;
    float* s_v   = R;
    float* s_sq  = R;
    float* s_x1  = R + 5120;
    float* c2t   = R;
    float* shW   = R;
    unsigned char* LeqB = (unsigned char*)(R + 1024);   // [9][256] bytes (row 8 = trash)

    const int t = threadIdx.x;
    const int b = blockIdx.x;

    // ---------------- stage inputs / weights ----------------
    float2 xv = ((const float2*)x)[b*NN + t];
    float sq0 = xv.x*xv.x + xv.y*xv.y;
    s_xyq[t*4+0] = xv.x; s_xyq[t*4+1] = xv.y; s_xyq[t*4+2] = sq0; s_xyq[t*4+3] = 0.f;
    if (t < 16) { s_b0[t] = c1_b0[t]; s_b1[t] = c1_b1[t]; s_b2[t] = c1_b2[t]; }
    if (t < 32) {
        int r = t >> 4, c = t & 15;
        float wt = c1_w0[r*16+c], wb = c1_w0[(2+r)*16+c];
        s_w0d[t] = wt - wb; s_w0b[t] = wb;
    }
    s_W1[t] = c1_w1[t]; s_W2[t] = c1_w2[t];
    if (t < 32) s_bc[t] = c2_b0[t];
    #pragma unroll
    for (int it = 0; it < 2; ++it) {
        int e = t + it*NN; int k = e >> 5, c = e & 31;
        float wt = c2_w0[k*32+c], wb = c2_w0[(16+k)*32+c];
        s_wtd[e] = wt - wb; s_wb[e] = wb;
    }
    __syncthreads();
    SB();

    // ---------------- P1: kNN on raw x (d=2), top-20 in registers ----------------
    {
        float r[KK];
        #pragma unroll
        for (int k = 0; k < KK; ++k) r[k] = __builtin_inff();
        #pragma unroll 4
        for (int j = 0; j < NN; ++j) {
            float d = dist2d(s_xyq, xv.x, xv.y, sq0, j, t);
            #pragma unroll
            for (int k = KK-1; k >= 1; --k) r[k] = med3f(d, r[k-1], r[k]);
            r[0] = fminf(r[0], d);
        }
        SB();
        // pass 2: recover indices (branchless append; stable tie-break via Leq quota)
        float V = r[KK-1];
        int cntL = 0, cntE = 0;
        #pragma unroll 4
        for (int j = 0; j < NN; ++j) {
            float d = dist2d(s_xyq, xv.x, xv.y, sq0, j, t);
            s_ki[min(cntL, KK)*NN + t] = (unsigned char)j;   // trash row if full
            cntL += (d < V) ? 1 : 0;
            if (d == V) { LeqB[min(cntE, 8)*NN + t] = (unsigned char)j; ++cntE; }
        }
        int need = KK - cntL;                                 // >= 1 always
        for (int e = 0; e < need; ++e)
            s_ki[(cntL + e)*NN + t] = LeqB[e*NN + t];
    }
    __syncthreads();   // all s_xyq reads done before s_v overwrites R[0..]
    SB();

    // ---------------- P2: conv1 (edge MLP 4->16->16->16, max over K) ----------------
    float u[16];
    {
        #pragma unroll
        for (int c = 0; c < 16; ++c) {
            u[c] = s_b0[c] + xv.x*s_w0d[c] + xv.y*s_w0d[16+c];
            s_v[t*20 + c] = xv.x*s_w0b[c] + xv.y*s_w0b[16+c];
        }
    }
    __syncthreads();
    SB();

    float x1f[16];
    {
        float acc[16];
        #pragma unroll
        for (int c = 0; c < 16; ++c) acc[c] = -FLT_MAX;
        #pragma unroll 1
        for (int p = 0; p < KK; p += 2) {
            int j0 = s_ki[p*NN + t], j1 = s_ki[(p+1)*NN + t];
            const float* va = s_v + j0*20;
            const float* vb = s_v + j1*20;
            float h1a[16], h1b[16];
            #pragma unroll
            for (int c = 0; c < 16; ++c) {
                h1a[c] = fmaxf(u[c] + va[c], 0.f);
                h1b[c] = fmaxf(u[c] + vb[c], 0.f);
            }
            float h2a[16], h2b[16];
            #pragma unroll
            for (int c = 0; c < 16; ++c) { h2a[c] = s_b1[c]; h2b[c] = s_b1[c]; }
            #pragma unroll
            for (int k = 0; k < 16; ++k) {
                float fa = h1a[k], fb = h1b[k];
                #pragma unroll
                for (int c = 0; c < 16; ++c) {
                    float w = s_W1[k*16+c];
                    h2a[c] = fmaf(fa, w, h2a[c]);
                    h2b[c] = fmaf(fb, w, h2b[c]);
                }
            }
            #pragma unroll
            for (int c = 0; c < 16; ++c) {
                h2a[c] = fmaxf(h2a[c], 0.f); h2b[c] = fmaxf(h2b[c], 0.f);
                h1a[c] = s_b2[c];            h1b[c] = s_b2[c];   // reuse as h3
            }
            #pragma unroll
            for (int k = 0; k < 16; ++k) {
                float fa = h2a[k], fb = h2b[k];
                #pragma unroll
                for (int c = 0; c < 16; ++c) {
                    float w = s_W2[k*16+c];
                    h1a[c] = fmaf(fa, w, h1a[c]);
                    h1b[c] = fmaf(fb, w, h1b[c]);
                }
            }
            #pragma unroll
            for (int c = 0; c < 16; ++c)
                acc[c] = fmaxf(acc[c], fmaxf(h1a[c], h1b[c]));
        }
        #pragma unroll
        for (int c = 0; c < 16; ++c) { s_x1[t*16 + c] = acc[c]; x1f[c] = acc[c]; }
    }
    float sq2 = 0.f;
    #pragma unroll
    for (int c = 0; c < 16; ++c) sq2 += x1f[c]*x1f[c];
    __syncthreads();          // all s_v reads done
    s_sq[t] = sq2;            // s_sq lives at R[0..255] (was s_v)
    __syncthreads();
    SB();

    // ---------------- P3: kNN on x1 (d=16), top-20 in registers ----------------
    {
        float r[KK];
        #pragma unroll
        for (int k = 0; k < KK; ++k) r[k] = __builtin_inff();
        #pragma unroll 2
        for (int j = 0; j < NN; ++j) {
            float d = dist16f(s_x1, s_sq, x1f, sq2, j, t);
            #pragma unroll
            for (int k = KK-1; k >= 1; --k) r[k] = med3f(d, r[k-1], r[k]);
            r[0] = fminf(r[0], d);
        }
        SB();
        float V = r[KK-1];
        int cntL = 0, cntE = 0;
        #pragma unroll 2
        for (int j = 0; j < NN; ++j) {
            float d = dist16f(s_x1, s_sq, x1f, sq2, j, t);
            s_ki[min(cntL, KK)*NN + t] = (unsigned char)j;
            cntL += (d < V) ? 1 : 0;
            if (d == V) { LeqB[min(cntE, 8)*NN + t] = (unsigned char)j; ++cntE; }
        }
        int need = KK - cntL;
        for (int e = 0; e < need; ++e)
            s_ki[(cntL + e)*NN + t] = LeqB[e*NN + t];
    }
    __syncthreads();
    SB();

    // ---------------- P4: conv2 (affine edge MLP 32->32; max commutes) ----------------
    float x2f[32];
    {
        float cj[32];
        #pragma unroll
        for (int c = 0; c < 32; ++c) cj[c] = 0.f;
        #pragma unroll
        for (int k = 0; k < 16; ++k) {
            float fk = x1f[k];
            #pragma unroll
            for (int c = 0; c < 32; ++c) cj[c] = fmaf(fk, s_wb[k*32+c], cj[c]);
        }
        #pragma unroll
        for (int c = 0; c < 32; ++c) c2t[c*NN + t] = cj[c];    // transposed store
        float ar[32];
        #pragma unroll
        for (int c = 0; c < 32; ++c) ar[c] = s_bc[c];
        #pragma unroll
        for (int k = 0; k < 16; ++k) {
            float fk = x1f[k];
            #pragma unroll
            for (int c = 0; c < 32; ++c) ar[c] = fmaf(fk, s_wtd[k*32+c], ar[c]);
        }
        __syncthreads();
        SB();
        float mx[32];
        #pragma unroll
        for (int c = 0; c < 32; ++c) mx[c] = -FLT_MAX;
        #pragma unroll 1
        for (int p = 0; p < KK; ++p) {
            int j = s_ki[p*NN + t];
            #pragma unroll
            for (int c = 0; c < 32; ++c) mx[c] = fmaxf(mx[c], c2t[c*NN + j]);
        }
        #pragma unroll
        for (int c = 0; c < 32; ++c) x2f[c] = ar[c] + mx[c];
    }
    __syncthreads();
    SB();

    // ---------------- P5: lin1 (48->128) + global max pool ----------------
    #pragma unroll 1
    for (int cc = 0; cc < 4; ++cc) {
        #pragma unroll
        for (int it = 0; it < 6; ++it) {
            int e = t + it*NN; int r = e >> 5, c = e & 31;
            shW[e] = lin1_w[r*128 + cc*32 + c];
        }
        __syncthreads();
        float accL[32];
        #pragma unroll
        for (int c = 0; c < 32; ++c) accL[c] = lin1_b[cc*32 + c];
        #pragma unroll
        for (int k = 0; k < 48; ++k) {
            float fk = (k < 16) ? x1f[k] : x2f[k-16];
            #pragma unroll
            for (int c = 0; c < 32; ++c) accL[c] = fmaf(fk, shW[k*32+c], accL[c]);
        }
        #pragma unroll
        for (int m = 1; m < 64; m <<= 1) {
            #pragma unroll
            for (int c = 0; c < 32; ++c)
                accL[c] = fmaxf(accL[c], __shfl_xor(accL[c], m, 64));
        }
        int w = t >> 6, lane = t & 63;
        if (lane == 0) {
            #pragma unroll
            for (int c = 0; c < 32; ++c) s_part[w*32 + c] = accL[c];
        }
        __syncthreads();
        if (t < 32) {
            float m0 = fmaxf(fmaxf(s_part[t], s_part[32+t]),
                             fmaxf(s_part[64+t], s_part[96+t]));
            s_pooled[cc*32 + t] = m0;
        }
        __syncthreads();
        SB();
    }

    // ---------------- P6: head MLP 128->64->64->1 ----------------
    if (t < 64) {
        float s = m_b0[t];
        #pragma unroll 8
        for (int k = 0; k < 128; ++k) s = fmaf(s_pooled[k], m_w0[k*64 + t], s);
        s_head[t] = fmaxf(s, 0.f);
    }
    __syncthreads();
    SB();
    if (t < 64) {
        float s = m_b1[t];
        #pragma unroll 8
        for (int k = 0; k < 64; ++k) s = fmaf(s_head[k], m_w1[k*64 + t], s);
        s = fmaxf(s, 0.f);
        float v = s * m_w2[t];
        #pragma unroll
        for (int m = 1; m < 64; m <<= 1) v += __shfl_xor(v, m, 64);
        if (t == 0) out[b] = v + m_b2[0];
    }
}

extern "C" void kernel_launch(void* const* d_in, const int* in_sizes, int n_in,
                              void* d_out, int out_size, void* d_ws, size_t ws_size,
                              hipStream_t stream) {
    const float* x    = (const float*)d_in[0];
    // d_in[1] = batch (int64) -- unused: batch ids are sorted, N per graph fixed
    const float* c1w0 = (const float*)d_in[2];
    const float* c1b0 = (const float*)d_in[3];
    const float* c1w1 = (const float*)d_in[4];
    const float* c1b1 = (const float*)d_in[5];
    const float* c1w2 = (const float*)d_in[6];
    const float* c1b2 = (const float*)d_in[7];
    const float* c2w0 = (const float*)d_in[8];
    const float* c2b0 = (const float*)d_in[9];
    const float* l1w  = (const float*)d_in[10];
    const float* l1b  = (const float*)d_in[11];
    const float* mw0  = (const float*)d_in[12];
    const float* mb0  = (const float*)d_in[13];
    const float* mw1  = (const float*)d_in[14];
    const float* mb1  = (const float*)d_in[15];
    const float* mw2  = (const float*)d_in[16];
    const float* mb2  = (const float*)d_in[17];
    float* out = (float*)d_out;
    hipLaunchKernelGGL(Net_35055523070563_kernel, dim3(512), dim3(256), 0, stream,
                       x, c1w0, c1b0, c1w1, c1b1, c1w2, c1b2, c2w0, c2b0,
                       l1w, l1b, mw0, mb0, mw1, mb1, mw2, mb2, out);
}

// Round 14
// 520.034 us; speedup vs baseline: 1.2265x; 1.2265x over previous
//
#include <hip/hip_runtime.h>
#include <float.h>

#define NN 256
#define KK 20

__device__ __forceinline__ float med3f(float a, float b, float c) {
    return __builtin_amdgcn_fmed3f(a, b, c);
}

// Distance helpers: called from BOTH pass1 (value top-k) and pass2 (index
// recovery) — identical inlined expression trees guarantee bit-identical d.
__device__ __forceinline__ float dist2d(const float* __restrict__ s_xyq,
                                        float xi0, float xi1, float sqi,
                                        int j, int t) {
    float4 q = ((const float4*)s_xyq)[j];          // uniform -> LDS broadcast
    float dot = xi0*q.x + xi1*q.y;
    float d = (sqi + q.z) - 2.0f*dot;
    return (j == t) ? __builtin_inff() : d;        // self-exclusion, branchless
}

__device__ __forceinline__ float dist16f(const float* __restrict__ s_x1,
                                         const float* __restrict__ s_sq,
                                         const float* __restrict__ x1f,
                                         float sq2, int j, int t) {
    const float4* xp = (const float4*)(s_x1 + (j << 4));   // uniform broadcast
    float4 q0 = xp[0], q1 = xp[1], q2 = xp[2], q3 = xp[3];
    float dot;
    dot  = x1f[0]*q0.x;  dot += x1f[1]*q0.y;  dot += x1f[2]*q0.z;  dot += x1f[3]*q0.w;
    dot += x1f[4]*q1.x;  dot += x1f[5]*q1.y;  dot += x1f[6]*q1.z;  dot += x1f[7]*q1.w;
    dot += x1f[8]*q2.x;  dot += x1f[9]*q2.y;  dot += x1f[10]*q2.z; dot += x1f[11]*q2.w;
    dot += x1f[12]*q3.x; dot += x1f[13]*q3.y; dot += x1f[14]*q3.z; dot += x1f[15]*q3.w;
    float d = (sq2 + s_sq[j]) - 2.0f*dot;
    return (j == t) ? __builtin_inff() : d;
}

// ============================ K1: kNN(x,d=2) + conv1 ============================
// Split rationale (r10 post-mortem): single-kernel builds pin VGPR at 256 and
// spill ~100MB/launch regardless of sched_barrier fences — IR-level hoisting of
// later phases' entry-known weight loads merges liveness across phases, and
// source-level fences can't stop it. Splitting bounds each unit's liveness by
// construction. K1 peak demand ~130 regs (conv1 E=2 block).
__global__ __launch_bounds__(256, 1)
void k1_knn1_conv1(const float* __restrict__ x,
                   const float* __restrict__ c1_w0, const float* __restrict__ c1_b0,
                   const float* __restrict__ c1_w1, const float* __restrict__ c1_b1,
                   const float* __restrict__ c1_w2, const float* __restrict__ c1_b2,
                   float* __restrict__ x1out)   // [512*256*16]
{
    // R multiplex: P1 s_xyq[1024] @0, LeqB bytes @ floats 1024..1599;
    //              P2 s_v[256*20] @0 (after barrier)
    __shared__ __align__(16) float R[5120];
    __shared__ unsigned char s_ki[(KK + 1) * NN];   // 20 rows + trash row
    __shared__ float s_w0d[32], s_w0b[32], s_b0[16], s_b1[16], s_b2[16];
    __shared__ __align__(16) float s_W1[256], s_W2[256];

    float* s_xyq = R;
    float* s_v   = R;
    unsigned char* LeqB = (unsigned char*)(R + 1024);   // [9][256] bytes

    const int t = threadIdx.x;
    const int b = blockIdx.x;

    float2 xv = ((const float2*)x)[b*NN + t];
    float sq0 = xv.x*xv.x + xv.y*xv.y;
    s_xyq[t*4+0] = xv.x; s_xyq[t*4+1] = xv.y; s_xyq[t*4+2] = sq0; s_xyq[t*4+3] = 0.f;
    if (t < 16) { s_b0[t] = c1_b0[t]; s_b1[t] = c1_b1[t]; s_b2[t] = c1_b2[t]; }
    if (t < 32) {
        int r = t >> 4, c = t & 15;
        float wt = c1_w0[r*16+c], wb = c1_w0[(2+r)*16+c];
        s_w0d[t] = wt - wb; s_w0b[t] = wb;
    }
    s_W1[t] = c1_w1[t]; s_W2[t] = c1_w2[t];
    __syncthreads();

    // ---- P1: kNN on raw x, top-20 values in registers (med3 chain) ----
    {
        float r[KK];
        #pragma unroll
        for (int k = 0; k < KK; ++k) r[k] = __builtin_inff();
        #pragma unroll 4
        for (int j = 0; j < NN; ++j) {
            float d = dist2d(s_xyq, xv.x, xv.y, sq0, j, t);
            #pragma unroll
            for (int k = KK-1; k >= 1; --k) r[k] = med3f(d, r[k-1], r[k]);
            r[0] = fminf(r[0], d);
        }
        // pass 2: index recovery (branchless; stable tie-break via Leq quota)
        float V = r[KK-1];
        int cntL = 0, cntE = 0;
        #pragma unroll 4
        for (int j = 0; j < NN; ++j) {
            float d = dist2d(s_xyq, xv.x, xv.y, sq0, j, t);
            s_ki[min(cntL, KK)*NN + t] = (unsigned char)j;   // trash row if full
            cntL += (d < V) ? 1 : 0;
            if (d == V) { LeqB[min(cntE, 8)*NN + t] = (unsigned char)j; ++cntE; }
        }
        int need = KK - cntL;                                 // >= 1 always
        for (int e = 0; e < need; ++e)
            s_ki[(cntL + e)*NN + t] = LeqB[e*NN + t];
    }
    __syncthreads();   // all s_xyq/LeqB reads done before s_v overwrites R

    // ---- P2: conv1 (edge MLP 4->16->16->16, max over K), E=2 ----
    float u[16];
    #pragma unroll
    for (int c = 0; c < 16; ++c) {
        u[c] = s_b0[c] + xv.x*s_w0d[c] + xv.y*s_w0d[16+c];
        s_v[t*20 + c] = xv.x*s_w0b[c] + xv.y*s_w0b[16+c];
    }
    __syncthreads();

    float acc[16];
    #pragma unroll
    for (int c = 0; c < 16; ++c) acc[c] = -FLT_MAX;
    #pragma unroll 1
    for (int p = 0; p < KK; p += 2) {
        int j0 = s_ki[p*NN + t], j1 = s_ki[(p+1)*NN + t];
        const float* va = s_v + j0*20;
        const float* vb = s_v + j1*20;
        float h1a[16], h1b[16];
        #pragma unroll
        for (int c = 0; c < 16; ++c) {
            h1a[c] = fmaxf(u[c] + va[c], 0.f);
            h1b[c] = fmaxf(u[c] + vb[c], 0.f);
        }
        float h2a[16], h2b[16];
        #pragma unroll
        for (int c = 0; c < 16; ++c) { h2a[c] = s_b1[c]; h2b[c] = s_b1[c]; }
        #pragma unroll
        for (int k = 0; k < 16; ++k) {
            float fa = h1a[k], fb = h1b[k];
            #pragma unroll
            for (int c = 0; c < 16; ++c) {
                float w = s_W1[k*16+c];
                h2a[c] = fmaf(fa, w, h2a[c]);
                h2b[c] = fmaf(fb, w, h2b[c]);
            }
        }
        #pragma unroll
        for (int c = 0; c < 16; ++c) {
            h2a[c] = fmaxf(h2a[c], 0.f); h2b[c] = fmaxf(h2b[c], 0.f);
            h1a[c] = s_b2[c];            h1b[c] = s_b2[c];   // reuse as h3
        }
        #pragma unroll
        for (int k = 0; k < 16; ++k) {
            float fa = h2a[k], fb = h2b[k];
            #pragma unroll
            for (int c = 0; c < 16; ++c) {
                float w = s_W2[k*16+c];
                h1a[c] = fmaf(fa, w, h1a[c]);
                h1b[c] = fmaf(fb, w, h1b[c]);
            }
        }
        #pragma unroll
        for (int c = 0; c < 16; ++c)
            acc[c] = fmaxf(acc[c], fmaxf(h1a[c], h1b[c]));
    }
    // coalesced 64B/lane store of x1
    float4* o = (float4*)(x1out + (b*NN + t)*16);
    o[0] = make_float4(acc[0],  acc[1],  acc[2],  acc[3]);
    o[1] = make_float4(acc[4],  acc[5],  acc[6],  acc[7]);
    o[2] = make_float4(acc[8],  acc[9],  acc[10], acc[11]);
    o[3] = make_float4(acc[12], acc[13], acc[14], acc[15]);
}

// ==================== K2: kNN(x1,d=16) + conv2 + lin1 + pool ====================
__global__ __launch_bounds__(256, 1)
void k2_knn2_conv2_lin1(const float* __restrict__ x1in,
                        const float* __restrict__ c2_w0, const float* __restrict__ c2_b0,
                        const float* __restrict__ lin1_w, const float* __restrict__ lin1_b,
                        float* __restrict__ pooled)   // [512*128]
{
    // R multiplex: s_x1[4096] @0, LeqB bytes @ floats 4096..4671;
    //              c2t[8192] @0 (after kNN2); shW[1536] @0 (after conv2 gather)
    __shared__ __align__(16) float R[8192];
    __shared__ unsigned char s_ki[(KK + 1) * NN];
    __shared__ float s_sq[NN];
    __shared__ __align__(16) float s_wtd[512], s_wb[512], s_bc[32];
    __shared__ float s_part[128];

    float* s_x1 = R;
    float* c2t  = R;
    float* shW  = R;
    unsigned char* LeqB = (unsigned char*)(R + 4096);

    const int t = threadIdx.x;
    const int b = blockIdx.x;

    // stage x1 -> regs + LDS; stage c2 weights (top/bottom split: affine max trick)
    float x1f[16];
    {
        const float4* ip = (const float4*)(x1in + (b*NN + t)*16);
        float4 a0 = ip[0], a1 = ip[1], a2 = ip[2], a3 = ip[3];
        x1f[0]=a0.x; x1f[1]=a0.y; x1f[2]=a0.z; x1f[3]=a0.w;
        x1f[4]=a1.x; x1f[5]=a1.y; x1f[6]=a1.z; x1f[7]=a1.w;
        x1f[8]=a2.x; x1f[9]=a2.y; x1f[10]=a2.z; x1f[11]=a2.w;
        x1f[12]=a3.x; x1f[13]=a3.y; x1f[14]=a3.z; x1f[15]=a3.w;
        float4* sp = (float4*)(s_x1 + t*16);
        sp[0]=a0; sp[1]=a1; sp[2]=a2; sp[3]=a3;
    }
    float sq2 = 0.f;
    #pragma unroll
    for (int c = 0; c < 16; ++c) sq2 += x1f[c]*x1f[c];
    s_sq[t] = sq2;
    if (t < 32) s_bc[t] = c2_b0[t];
    #pragma unroll
    for (int it = 0; it < 2; ++it) {
        int e = t + it*NN; int k = e >> 5, c = e & 31;
        float wt = c2_w0[k*32+c], wb = c2_w0[(16+k)*32+c];
        s_wtd[e] = wt - wb; s_wb[e] = wb;
    }
    __syncthreads();

    // ---- P3: kNN on x1, top-20 in registers ----
    {
        float r[KK];
        #pragma unroll
        for (int k = 0; k < KK; ++k) r[k] = __builtin_inff();
        #pragma unroll 2
        for (int j = 0; j < NN; ++j) {
            float d = dist16f(s_x1, s_sq, x1f, sq2, j, t);
            #pragma unroll
            for (int k = KK-1; k >= 1; --k) r[k] = med3f(d, r[k-1], r[k]);
            r[0] = fminf(r[0], d);
        }
        float V = r[KK-1];
        int cntL = 0, cntE = 0;
        #pragma unroll 2
        for (int j = 0; j < NN; ++j) {
            float d = dist16f(s_x1, s_sq, x1f, sq2, j, t);
            s_ki[min(cntL, KK)*NN + t] = (unsigned char)j;
            cntL += (d < V) ? 1 : 0;
            if (d == V) { LeqB[min(cntE, 8)*NN + t] = (unsigned char)j; ++cntE; }
        }
        int need = KK - cntL;
        for (int e = 0; e < need; ++e)
            s_ki[(cntL + e)*NN + t] = LeqB[e*NN + t];
    }
    __syncthreads();   // all s_x1/LeqB reads done before c2t overwrites R

    // ---- P4: conv2 (affine edge MLP 32->32; max commutes with affine) ----
    float x2f[32];
    {
        float cj[32];
        #pragma unroll
        for (int c = 0; c < 32; ++c) cj[c] = 0.f;
        #pragma unroll
        for (int k = 0; k < 16; ++k) {
            float fk = x1f[k];
            #pragma unroll
            for (int c = 0; c < 32; ++c) cj[c] = fmaf(fk, s_wb[k*32+c], cj[c]);
        }
        #pragma unroll
        for (int c = 0; c < 32; ++c) c2t[c*NN + t] = cj[c];    // transposed store
        float ar[32];
        #pragma unroll
        for (int c = 0; c < 32; ++c) ar[c] = s_bc[c];
        #pragma unroll
        for (int k = 0; k < 16; ++k) {
            float fk = x1f[k];
            #pragma unroll
            for (int c = 0; c < 32; ++c) ar[c] = fmaf(fk, s_wtd[k*32+c], ar[c]);
        }
        __syncthreads();
        float mx[32];
        #pragma unroll
        for (int c = 0; c < 32; ++c) mx[c] = -FLT_MAX;
        #pragma unroll 1
        for (int p = 0; p < KK; ++p) {
            int j = s_ki[p*NN + t];
            #pragma unroll
            for (int c = 0; c < 32; ++c) mx[c] = fmaxf(mx[c], c2t[c*NN + j]);
        }
        #pragma unroll
        for (int c = 0; c < 32; ++c) x2f[c] = ar[c] + mx[c];
    }
    __syncthreads();   // c2t reads done before shW overwrites R

    // ---- P5: lin1 (48->128) + global max pool -> pooled ----
    #pragma unroll 1
    for (int cc = 0; cc < 4; ++cc) {
        #pragma unroll
        for (int it = 0; it < 6; ++it) {
            int e = t + it*NN; int r = e >> 5, c = e & 31;
            shW[e] = lin1_w[r*128 + cc*32 + c];
        }
        __syncthreads();
        float accL[32];
        #pragma unroll
        for (int c = 0; c < 32; ++c) accL[c] = lin1_b[cc*32 + c];
        #pragma unroll
        for (int k = 0; k < 48; ++k) {
            float fk = (k < 16) ? x1f[k] : x2f[k-16];
            #pragma unroll
            for (int c = 0; c < 32; ++c) accL[c] = fmaf(fk, shW[k*32+c], accL[c]);
        }
        #pragma unroll
        for (int m = 1; m < 64; m <<= 1) {
            #pragma unroll
            for (int c = 0; c < 32; ++c)
                accL[c] = fmaxf(accL[c], __shfl_xor(accL[c], m, 64));
        }
        int w = t >> 6, lane = t & 63;
        if (lane == 0) {
            #pragma unroll
            for (int c = 0; c < 32; ++c) s_part[w*32 + c] = accL[c];
        }
        __syncthreads();
        if (t < 32) {
            float m0 = fmaxf(fmaxf(s_part[t], s_part[32+t]),
                             fmaxf(s_part[64+t], s_part[96+t]));
            pooled[b*128 + cc*32 + t] = m0;
        }
        __syncthreads();
    }
}

// ============================ K3: head MLP 128->64->64->1 ============================
__global__ __launch_bounds__(64, 1)
void k3_head(const float* __restrict__ pooled,
             const float* __restrict__ m_w0, const float* __restrict__ m_b0,
             const float* __restrict__ m_w1, const float* __restrict__ m_b1,
             const float* __restrict__ m_w2, const float* __restrict__ m_b2,
             float* __restrict__ out)
{
    __shared__ float s_p[128], s_head[64];
    const int t = threadIdx.x;
    const int b = blockIdx.x;
    s_p[t]      = pooled[b*128 + t];
    s_p[t + 64] = pooled[b*128 + 64 + t];
    __syncthreads();
    float s = m_b0[t];
    #pragma unroll 8
    for (int k = 0; k < 128; ++k) s = fmaf(s_p[k], m_w0[k*64 + t], s);
    s_head[t] = fmaxf(s, 0.f);
    __syncthreads();
    s = m_b1[t];
    #pragma unroll 8
    for (int k = 0; k < 64; ++k) s = fmaf(s_head[k], m_w1[k*64 + t], s);
    s = fmaxf(s, 0.f);
    float v = s * m_w2[t];
    #pragma unroll
    for (int m = 1; m < 64; m <<= 1) v += __shfl_xor(v, m, 64);
    if (t == 0) out[b] = v + m_b2[0];
}

extern "C" void kernel_launch(void* const* d_in, const int* in_sizes, int n_in,
                              void* d_out, int out_size, void* d_ws, size_t ws_size,
                              hipStream_t stream) {
    const float* x    = (const float*)d_in[0];
    // d_in[1] = batch (int64) -- unused: batch ids are sorted, N per graph fixed
    const float* c1w0 = (const float*)d_in[2];
    const float* c1b0 = (const float*)d_in[3];
    const float* c1w1 = (const float*)d_in[4];
    const float* c1b1 = (const float*)d_in[5];
    const float* c1w2 = (const float*)d_in[6];
    const float* c1b2 = (const float*)d_in[7];
    const float* c2w0 = (const float*)d_in[8];
    const float* c2b0 = (const float*)d_in[9];
    const float* l1w  = (const float*)d_in[10];
    const float* l1b  = (const float*)d_in[11];
    const float* mw0  = (const float*)d_in[12];
    const float* mb0  = (const float*)d_in[13];
    const float* mw1  = (const float*)d_in[14];
    const float* mb1  = (const float*)d_in[15];
    const float* mw2  = (const float*)d_in[16];
    const float* mb2  = (const float*)d_in[17];
    float* out = (float*)d_out;

    // d_ws layout: x1 [512*256*16 f32] @ 0 (8 MB), pooled [512*128 f32] after.
    float* ws     = (float*)d_ws;
    float* x1buf  = ws;
    float* plbuf  = ws + (size_t)512*256*16;

    hipLaunchKernelGGL(k1_knn1_conv1, dim3(512), dim3(256), 0, stream,
                       x, c1w0, c1b0, c1w1, c1b1, c1w2, c1b2, x1buf);
    hipLaunchKernelGGL(k2_knn2_conv2_lin1, dim3(512), dim3(256), 0, stream,
                       x1buf, c2w0, c2b0, l1w, l1b, plbuf);
    hipLaunchKernelGGL(k3_head, dim3(512), dim3(64), 0, stream,
                       plbuf, mw0, mb0, mw1, mb1, mw2, mb2, out);
}